// Round 7
// baseline (205.076 us; speedup 1.0000x reference)
//
#include <hip/hip_runtime.h>

// Flow1: RealNVP coupling flow. K=32 B=4096 ZS=128 ZH=64 HS=50 NF=2.
// Round 11: revert r10's swapped-operand layout (regressed 71->80 us; bank
// conflicts 3x = +1M stall cycles, VALU-busy time unchanged -> paid stall to
// save VALU we didn't need). Back to r9 orientation, push the ILP axis that
// measurably works (r8->r9: 1->2 tiles = -16 us):
//   4 M-tiles (64 rows) per wave, one wave per 64-thread block, grid 2048.
//   Weight frags + biases loaded once per step, shared by 4 independent
//   MFMA/tanh/sigmoid chains. Grid is TLP-exhausted (4 waves/SIMD of total
//   work) so per-wave ILP is the only concurrency left.
// VGPR ~210 expected (128 state + working); NO launch_bounds min-waves (it
// halves the arch budget - proven r5/r6). Tripwires: WRITE_SIZE>70MB = spill
// (drop to 3-tile); VALUBusy down w/o conflict change = I$ (split do_step).
//
// Layouts (m89/m91-verified):
//   A-frag: A[m][k], m=lane&15, k=quad*8+j (j=0..7) per 32-K-tile
//   B-frag: B[k][n], n=lane&15, k=quad*8+j
//   C/D   : D[m][n], n=lane&15, m=quad*4+reg

typedef unsigned short ushort_t;
typedef unsigned int   uint_t;
typedef short bf8 __attribute__((ext_vector_type(8)));
typedef float f4  __attribute__((ext_vector_type(4)));

#define KK   32
#define BB   4096
#define ZSD  128
#define ZHD  64
#define HSD  50
#define NROWS (KK*BB)
#define NT4  4                    // M-tiles per wave

#define WST  72                   // k-stride (shorts) for weight/act tiles
#define MATS (64*WST)             // shorts per padded matrix  = 4608
#define WGL_SHORTS (12*MATS)      // 55296 shorts = 110592 B
#define WS_BYTES   (WGL_SHORTS*2 + 768*4)   // + padded fp32 biases [4][3][64]

__device__ __forceinline__ float bf2f(ushort_t u){ union{uint_t i; float f;} v; v.i = ((uint_t)u)<<16; return v.f; }

// hardware bf16 convert (RNE on gfx950)
__device__ __forceinline__ ushort_t f2bf(float f){
  union{__bf16 h; ushort_t u;} v; v.h = (__bf16)f; return v.u;
}

__device__ __forceinline__ float rcp_fast(float x){ return __builtin_amdgcn_rcpf(x); }

__device__ __forceinline__ float tanh_fast(float x){
  float ax = fabsf(x);
  float t  = __expf(-2.0f*ax);                  // (0,1]
  float r  = (1.0f - t) * rcp_fast(1.0f + t);
  union{float f; uint_t i;} u, s; u.f = r; s.f = x;
  u.i |= (s.i & 0x80000000u);
  return u.f;
}

// sigmoid only (log handled via product accumulation outside)
__device__ __forceinline__ float sigmoid_fast(float x){
  float ax  = fabsf(x);
  float e   = __expf(-ax);
  float inv = rcp_fast(1.0f + e);
  return (x >= 0.0f) ? inv : e*inv;
}

__device__ __forceinline__ f4 MFMA(bf8 a, bf8 b, f4 c){
  return __builtin_amdgcn_mfma_f32_16x16x32_bf16(a, b, c, 0, 0, 0);
}

// ---- weight preconversion: fp32 -> padded bf16 [step][mat][n][WST] + biases
__global__ void convert_weights(const float* __restrict__ W0g,
                                const float* __restrict__ b0g,
                                const float* __restrict__ W1g,
                                const float* __restrict__ b1g,
                                const float* __restrict__ W2g,
                                const float* __restrict__ b2g,
                                ushort_t* __restrict__ wgl)
{
  int t = blockIdx.x*256 + threadIdx.x;
  if (t < WGL_SHORTS){
    int mi  = t / MATS;             // step*3 + which
    int rem = t % MATS;
    int n   = rem / WST;
    int k   = rem % WST;
    int step  = mi / 3;
    int which = mi % 3;
    float v = 0.0f;
    if (which == 0){                           // B0[k=z][n=h] = W0[step][n][k]
      if (n < HSD && k < ZHD) v = W0g[(step*HSD + n)*ZHD + k];
    } else if (which == 1){                    // B1[k=h][n=z] = W1[step][n][k]
      if (k < HSD)            v = W1g[(step*ZHD + n)*HSD + k];
    } else {
      if (k < HSD)            v = W2g[(step*ZHD + n)*HSD + k];
    }
    wgl[t] = f2bf(v);
  }
  if (t < 768){                                // biases fp32 padded to 64
    float* bp = (float*)(wgl + WGL_SHORTS);
    int step  = t / 192;
    int rem   = t % 192;
    int which = rem / 64;
    int n     = rem % 64;
    float v = 0.0f;
    if (which == 0){ if (n < HSD) v = b0g[step*HSD + n]; }
    else if (which == 1) v = b1g[step*ZHD + n];
    else                 v = b2g[step*ZHD + n];
    bp[t] = v;
  }
}

// one coupling step; pz = passive-half registers (4 M-tiles, updated),
// active halves already in zAw
__device__ __forceinline__ void do_step(
    int s, float (&pz)[NT4][16], float (&T)[NT4][4],
    ushort_t* zAw, ushort_t* hAw,
    const ushort_t* wgl, const float* wsb,
    int quad, int l15, int wr)
{
  // this step's 3 matrices, read directly from global (L1/L2-resident)
  const ushort_t* ws = wgl + (size_t)(s*3)*MATS;

  // ---- phase A: H = tanh(Zact @ B0 + b0) ----
  bf8 zf[NT4][2];
  #pragma unroll
  for (int m=0;m<NT4;++m)
    #pragma unroll
    for (int kt=0;kt<2;++kt)
      zf[m][kt] = *(const bf8*)(zAw + (m*16 + l15)*WST + kt*32 + quad*8);

  #pragma unroll
  for (int nt=0;nt<4;++nt){
    const ushort_t* wb = ws + (0*64 + nt*16 + l15)*WST + quad*8;
    bf8 w0a = *(const bf8*)(wb);
    bf8 w0b = *(const bf8*)(wb + 32);
    float b0v = wsb[(s*3+0)*64 + nt*16 + l15];
    #pragma unroll
    for (int m=0;m<NT4;++m){
      f4 acc = {0.f,0.f,0.f,0.f};
      acc = MFMA(zf[m][0], w0a, acc);
      acc = MFMA(zf[m][1], w0b, acc);
      #pragma unroll
      for (int i=0;i<4;++i){
        float h = tanh_fast(acc[i] + b0v);
        hAw[(m*16 + quad*4 + i)*WST + nt*16 + l15] = f2bf(h);
      }
    }
  }

  // ---- phase B: MEW = H@B1 + b1 ; SIG = sigmoid(H@B2 + b2) ----
  bf8 hf[NT4][2];
  #pragma unroll
  for (int m=0;m<NT4;++m)
    #pragma unroll
    for (int kt=0;kt<2;++kt)
      hf[m][kt] = *(const bf8*)(hAw + (m*16 + l15)*WST + kt*32 + quad*8);

  // product-of-sigmoids accumulators: one log per (m,i) per step
  float sp[NT4][4];
  #pragma unroll
  for (int m=0;m<NT4;++m)
    #pragma unroll
    for (int i=0;i<4;++i) sp[m][i] = 1.0f;

  #pragma unroll
  for (int nt=0;nt<4;++nt){
    const ushort_t* w1p = ws + (1*64 + nt*16 + l15)*WST + quad*8;
    const ushort_t* w2p = ws + (2*64 + nt*16 + l15)*WST + quad*8;
    bf8 w1a = *(const bf8*)(w1p);
    bf8 w1b = *(const bf8*)(w1p + 32);
    bf8 w2a = *(const bf8*)(w2p);
    bf8 w2b = *(const bf8*)(w2p + 32);
    float b1v = wsb[(s*3+1)*64 + nt*16 + l15];
    float b2v = wsb[(s*3+2)*64 + nt*16 + l15];
    #pragma unroll
    for (int m=0;m<NT4;++m){
      f4 am = {0.f,0.f,0.f,0.f};
      f4 as = {0.f,0.f,0.f,0.f};
      am = MFMA(hf[m][0], w1a, am);
      am = MFMA(hf[m][1], w1b, am);
      as = MFMA(hf[m][0], w2a, as);
      as = MFMA(hf[m][1], w2b, as);
      #pragma unroll
      for (int i=0;i<4;++i){
        float mew  = am[i] + b1v;
        float spre = as[i] + b2v;
        float sig  = sigmoid_fast(spre);
        sp[m][i] *= sig;
        pz[m][nt*4+i] = fmaf(pz[m][nt*4+i], sig, mew);
      }
    }
  }

  // 4-term products >= (7.5e-4)^4 ~ 3e-13: safely above fp32 underflow
  #pragma unroll
  for (int m=0;m<NT4;++m)
    #pragma unroll
    for (int i=0;i<4;++i)
      T[m][i] += __logf(sp[m][i]);

  // new active = just-updated passive -> zA (bf16, A-layout)
  if (wr){
    #pragma unroll
    for (int m=0;m<NT4;++m)
      #pragma unroll
      for (int nt=0;nt<4;++nt)
        #pragma unroll
        for (int i=0;i<4;++i)
          zAw[(m*16 + quad*4 + i)*WST + nt*16 + l15] = f2bf(pz[m][nt*4+i]);
  }
}

__global__ __launch_bounds__(64) void flow_mfma(
    const float* __restrict__ mean, const float* __restrict__ logvar,
    const float* __restrict__ eps,
    const ushort_t* __restrict__ wgl,
    float* __restrict__ out)
{
  __shared__ __align__(16) ushort_t zA[64*WST];         // 9216 B
  __shared__ __align__(16) ushort_t hA[64*WST];         // 9216 B

  const int lane = threadIdx.x;     // 64-thread block = 1 wave
  const int quad = lane >> 4;
  const int l15  = lane & 15;
  const int rbase = blockIdx.x*64;

  const float* wsb = (const float*)(wgl + WGL_SHORTS);
  ushort_t* zAw = zA;
  ushort_t* hAw = hA;

  // z1D/z2D in C/D layout: [mtile][nt*4+reg] -> row=mtile*16+quad*4+reg,
  // col(z-index within half)=nt*16+l15
  float z1D[NT4][16], z2D[NT4][16];
  float T[NT4][4];                   // T = 0.5*sum(lv+eps^2) + sum(lsig)

  // ---- init: z = eps*exp(0.5*lv)+mean, loaded directly in D-layout ----
  #pragma unroll
  for (int m=0;m<NT4;++m){
    #pragma unroll
    for (int i=0;i<4;++i){
      int rrow = rbase + m*16 + quad*4 + i;
      int brow = rrow & (BB-1);
      const float* er = eps    + (size_t)rrow*ZSD;
      const float* mr = mean   + (size_t)brow*ZSD;
      const float* vr = logvar + (size_t)brow*ZSD;
      float acc = 0.f;
      #pragma unroll
      for (int nt=0;nt<4;++nt){
        int c1 = nt*16 + l15;
        int c2 = 64 + c1;
        float e1 = er[c1], v1 = vr[c1], m1 = mr[c1];
        float e2 = er[c2], v2 = vr[c2], m2 = mr[c2];
        z1D[m][nt*4+i] = fmaf(e1, __expf(0.5f*v1), m1);
        z2D[m][nt*4+i] = fmaf(e2, __expf(0.5f*v2), m2);
        acc += (v1 + e1*e1) + (v2 + e2*e2);
      }
      T[m][i] = 0.5f*acc;
    }
  }

  // initial active = z1 -> zA
  #pragma unroll
  for (int m=0;m<NT4;++m)
    #pragma unroll
    for (int nt=0;nt<4;++nt)
      #pragma unroll
      for (int i=0;i<4;++i)
        zAw[(m*16 + quad*4 + i)*WST + nt*16 + l15] = f2bf(z1D[m][nt*4+i]);

  // ---- 4 coupling steps (2 bodies in a non-unrolled loop to bound I$) ----
  #pragma unroll 1
  for (int it=0; it<2; ++it){
    do_step(2*it+0, z2D, T, zAw, hAw, wgl, wsb, quad, l15, 1);
    do_step(2*it+1, z1D, T, zAw, hAw, wgl, wsb, quad, l15, it==0);
  }

  // ---- store z_out (fp32) ----
  #pragma unroll
  for (int m=0;m<NT4;++m){
    #pragma unroll
    for (int i=0;i<4;++i){
      int rrow = rbase + m*16 + quad*4 + i;
      float* orow = out + (size_t)rrow*ZSD;
      #pragma unroll
      for (int nt=0;nt<4;++nt){
        orow[nt*16 + l15]      = z1D[m][nt*4+i];
        orow[64 + nt*16 + l15] = z2D[m][nt*4+i];
      }
    }
  }

  // ---- logpz = -0.5*128*ln(2pi) - T_rowsum ; reduce T across the 16 lanes
  // of each quad (they cover all 128 cols of rows quad*4+reg) ----
  #pragma unroll
  for (int m=0;m<NT4;++m)
    #pragma unroll
    for (int i=0;i<4;++i){
      float v = T[m][i];
      v += __shfl_xor(v, 1, 64);
      v += __shfl_xor(v, 2, 64);
      v += __shfl_xor(v, 4, 64);
      v += __shfl_xor(v, 8, 64);
      T[m][i] = v;
    }
  if (l15 == 0){
    const float NC = -0.5f * 128.0f * 1.8378770664093453f;
    #pragma unroll
    for (int m=0;m<NT4;++m)
      #pragma unroll
      for (int i=0;i<4;++i){
        int rrow = rbase + m*16 + quad*4 + i;
        out[(size_t)NROWS*ZSD + rrow] = NC - T[m][i];
      }
  }
}

extern "C" void kernel_launch(void* const* d_in, const int* in_sizes, int n_in,
                              void* d_out, int out_size, void* d_ws, size_t ws_size,
                              hipStream_t stream)
{
  const float* mean   = (const float*)d_in[0];
  const float* logvar = (const float*)d_in[1];
  const float* eps    = (const float*)d_in[2];
  const float* W0     = (const float*)d_in[3];
  const float* b0     = (const float*)d_in[4];
  const float* W1     = (const float*)d_in[5];
  const float* b1     = (const float*)d_in[6];
  const float* W2     = (const float*)d_in[7];
  const float* b2     = (const float*)d_in[8];
  ushort_t* wgl = (ushort_t*)d_ws;          // ws_size >= 156448 proven round 3

  convert_weights<<<(WGL_SHORTS + 255)/256, 256, 0, stream>>>(W0,b0,W1,b1,W2,b2, wgl);
  flow_mfma<<<NROWS/64, 64, 0, stream>>>(mean, logvar, eps, wgl, (float*)d_out);
}

// Round 8
// 183.951 us; speedup vs baseline: 1.1148x; 1.1148x over previous
//
#include <hip/hip_runtime.h>

// Flow1: RealNVP coupling flow. K=32 B=4096 ZS=128 ZH=64 HS=50 NF=2.
// Round 12: LDS-FREE. r11 proved wave count matters (2048 waves = 103 us vs
// r9's 4096 = 71 us); back to 2-tile/128-thr/4096-wave shape. The remaining
// serial cost in r9 is the D-layout->A-frag transpose through LDS (64 scalar
// ds_write_b16 + 8 ds_read_b128 per step, ~120cy chains). This round uses
// r10's swapped orientation (A=W from global, B=Z^T/H^T; D holds cols q*4+i
// per lane) and does the frag regroup IN REGISTERS:
//   pack f4 -> 2 bf16 dwords (cvt_pk), then per kt:
//   permlane32_swap + permlane16_swap on (P[2kt][d], P[2kt+1][d])
//   -> bf8 dwords {F0,F2},{F1,F3}.  8 cvt_pk + 8 permlane per fragment.
// Kernel has ZERO LDS / barriers / lgkm waits / bank conflicts. Also keeps
// r10's f4 init loads, f4 biases, f4 output stores (r10's regression was the
// LDS bank conflicts, now structurally gone).
//
// Frag layouts (m89/m91-verified):
//   A-frag: A[m][k], m=lane&15, k=quad*8+j (j=0..7) per 32-K-tile
//   B-frag: B[k][n], n=lane&15, k=quad*8+j
//   C/D   : D[m][n], n=lane&15, m=quad*4+reg
// permlane swaps (LLVM gfx950): swap32: a'={a[0:31],b[0:31]}, b'={a[32:63],
// b[32:63]}; swap16: a'={a_r0,b_r0,a_r2,b_r2}, b'={a_r1,b_r1,a_r3,b_r3}
// (16-lane rows).

typedef unsigned short ushort_t;
typedef unsigned int   uint_t;
typedef short bf8 __attribute__((ext_vector_type(8)));
typedef float f4  __attribute__((ext_vector_type(4)));

#define KK   32
#define BB   4096
#define ZSD  128
#define ZHD  64
#define HSD  50
#define NROWS (KK*BB)

#define WST  72                   // k-stride (shorts) for weight tiles
#define MATS (64*WST)             // shorts per padded matrix  = 4608
#define WGL_SHORTS (12*MATS)      // 55296 shorts = 110592 B
#define WS_BYTES   (WGL_SHORTS*2 + 768*4)   // + padded fp32 biases [4][3][64]

// hardware bf16 convert (RNE on gfx950)
__device__ __forceinline__ ushort_t f2bf(float f){
  union{__bf16 h; ushort_t u;} v; v.h = (__bf16)f; return v.u;
}
__device__ __forceinline__ uint_t pkbf(float lo, float hi){
  return (uint_t)f2bf(lo) | ((uint_t)f2bf(hi) << 16);
}

__device__ __forceinline__ float rcp_fast(float x){ return __builtin_amdgcn_rcpf(x); }

__device__ __forceinline__ float tanh_fast(float x){
  float ax = fabsf(x);
  float t  = __expf(-2.0f*ax);                  // (0,1]
  float r  = (1.0f - t) * rcp_fast(1.0f + t);
  union{float f; uint_t i;} u, s; u.f = r; s.f = x;
  u.i |= (s.i & 0x80000000u);
  return u.f;
}

// sigmoid only (log handled via product accumulation outside)
__device__ __forceinline__ float sigmoid_fast(float x){
  float ax  = fabsf(x);
  float e   = __expf(-ax);
  float inv = rcp_fast(1.0f + e);
  return (x >= 0.0f) ? inv : e*inv;
}

__device__ __forceinline__ f4 MFMA(bf8 a, bf8 b, f4 c){
  return __builtin_amdgcn_mfma_f32_16x16x32_bf16(a, b, c, 0, 0, 0);
}

// D-layout (cols quad*4+i per lane) -> B-frag(X^T) (cols quad*8+j), in-reg.
// v[nt*4+i] = this lane's col nt*16+quad*4+i of its row. Produces zf[kt]
// with elems j = col kt*32+quad*8+j. 8 cvt_pk + 8 permlane, no LDS.
__device__ __forceinline__ void dtofrag(const float* v, bf8* zf){
  uint_t P[4][2];
  #pragma unroll
  for (int nt=0;nt<4;++nt){
    P[nt][0] = pkbf(v[nt*4+0], v[nt*4+1]);
    P[nt][1] = pkbf(v[nt*4+2], v[nt*4+3]);
  }
  #pragma unroll
  for (int kt=0;kt<2;++kt){
    uint_t a0 = P[2*kt][0], b0 = P[2*kt+1][0];
    uint_t a1 = P[2*kt][1], b1 = P[2*kt+1][1];
    asm("v_permlane32_swap_b32 %0, %1" : "+v"(a0), "+v"(b0));
    asm("v_permlane16_swap_b32 %0, %1" : "+v"(a0), "+v"(b0));
    asm("v_permlane32_swap_b32 %0, %1" : "+v"(a1), "+v"(b1));
    asm("v_permlane16_swap_b32 %0, %1" : "+v"(a1), "+v"(b1));
    union { uint_t d[4]; bf8 v8; } u;
    u.d[0]=a0; u.d[1]=a1; u.d[2]=b0; u.d[3]=b1;
    zf[kt]=u.v8;
  }
}

// ---- weight preconversion: fp32 -> padded bf16 [step][mat][n][WST] + biases
// storage[n][k]: mat0 = W0[h=n][z=k], mat1 = W1[z=n][h=k], mat2 = W2[z=n][h=k]
// serves as A-frag for the swapped orientation (r10-verified on HW)
__global__ void convert_weights(const float* __restrict__ W0g,
                                const float* __restrict__ b0g,
                                const float* __restrict__ W1g,
                                const float* __restrict__ b1g,
                                const float* __restrict__ W2g,
                                const float* __restrict__ b2g,
                                ushort_t* __restrict__ wgl)
{
  int t = blockIdx.x*256 + threadIdx.x;
  if (t < WGL_SHORTS){
    int mi  = t / MATS;             // step*3 + which
    int rem = t % MATS;
    int n   = rem / WST;
    int k   = rem % WST;
    int step  = mi / 3;
    int which = mi % 3;
    float v = 0.0f;
    if (which == 0){
      if (n < HSD && k < ZHD) v = W0g[(step*HSD + n)*ZHD + k];
    } else if (which == 1){
      if (k < HSD)            v = W1g[(step*ZHD + n)*HSD + k];
    } else {
      if (k < HSD)            v = W2g[(step*ZHD + n)*HSD + k];
    }
    wgl[t] = f2bf(v);
  }
  if (t < 768){                                // biases fp32 padded to 64
    float* bp = (float*)(wgl + WGL_SHORTS);
    int step  = t / 192;
    int rem   = t % 192;
    int which = rem / 64;
    int n     = rem % 64;
    float v = 0.0f;
    if (which == 0){ if (n < HSD) v = b0g[step*HSD + n]; }
    else if (which == 1) v = b1g[step*ZHD + n];
    else                 v = b2g[step*ZHD + n];
    bp[t] = v;
  }
}

// one coupling step (swapped operands, LDS-free).
// az = active half (read-only, D-layout regs), pz = passive half (updated).
__device__ __forceinline__ void do_step(
    int s, const float (&az)[2][16], float (&pz)[2][16], float (&T)[2],
    const ushort_t* wgl, const float* wsb,
    int quad, int l15)
{
  const ushort_t* ws = wgl + (size_t)(s*3)*MATS;
  const float* bp0 = wsb + (s*3+0)*64;
  const float* bp1 = wsb + (s*3+1)*64;
  const float* bp2 = wsb + (s*3+2)*64;
  const int qc = quad*4;

  // ---- active -> B-frags, in-register ----
  bf8 zf[2][2];
  #pragma unroll
  for (int t=0;t<2;++t) dtofrag(az[t], zf[t]);

  // ---- phase A: H^T = W0 . Z^T ; h = tanh(. + b0) ----
  float hrow[2][16];
  #pragma unroll
  for (int nt=0;nt<4;++nt){
    const ushort_t* wb = ws + (0*64 + nt*16 + l15)*WST + quad*8;   // A-frag(W0)
    bf8 a0  = *(const bf8*)(wb);
    bf8 a0b = *(const bf8*)(wb + 32);
    f4 b0v  = *(const f4*)(bp0 + nt*16 + qc);
    #pragma unroll
    for (int t=0;t<2;++t){
      f4 acc = {0.f,0.f,0.f,0.f};
      acc = MFMA(a0,  zf[t][0], acc);
      acc = MFMA(a0b, zf[t][1], acc);
      #pragma unroll
      for (int i=0;i<4;++i)
        hrow[t][nt*4+i] = tanh_fast(acc[i] + b0v[i]);
    }
  }

  // ---- H -> B-frags, in-register ----
  bf8 hf[2][2];
  #pragma unroll
  for (int t=0;t<2;++t) dtofrag(hrow[t], hf[t]);

  // ---- phase B: MEW^T = W1.H^T + b1 ; SIG^T = sigmoid(W2.H^T + b2) ----
  float spa[2] = {1.0f, 1.0f}, spb[2] = {1.0f, 1.0f};
  #pragma unroll
  for (int nt=0;nt<4;++nt){
    const ushort_t* w1p = ws + (1*64 + nt*16 + l15)*WST + quad*8;  // A-frag(W1)
    const ushort_t* w2p = ws + (2*64 + nt*16 + l15)*WST + quad*8;  // A-frag(W2)
    bf8 a1  = *(const bf8*)(w1p);
    bf8 a1b = *(const bf8*)(w1p + 32);
    bf8 a2  = *(const bf8*)(w2p);
    bf8 a2b = *(const bf8*)(w2p + 32);
    f4 b1v = *(const f4*)(bp1 + nt*16 + qc);
    f4 b2v = *(const f4*)(bp2 + nt*16 + qc);
    #pragma unroll
    for (int t=0;t<2;++t){
      f4 am = {0.f,0.f,0.f,0.f};
      f4 as = {0.f,0.f,0.f,0.f};
      am = MFMA(a1,  hf[t][0], am);
      am = MFMA(a1b, hf[t][1], am);
      as = MFMA(a2,  hf[t][0], as);
      as = MFMA(a2b, hf[t][1], as);
      #pragma unroll
      for (int i=0;i<4;++i){
        float mew  = am[i] + b1v[i];
        float spre = as[i] + b2v[i];
        float sig  = sigmoid_fast(spre);
        if (nt < 2) spa[t] *= sig; else spb[t] *= sig;
        pz[t][nt*4+i] = fmaf(pz[t][nt*4+i], sig, mew);
      }
    }
  }
  // 8-term products >= (7.5e-4)^8 ~ 1e-25: safely above fp32 underflow
  #pragma unroll
  for (int t=0;t<2;++t)
    T[t] += __logf(spa[t]) + __logf(spb[t]);
}

__global__ __launch_bounds__(128) void flow_mfma(
    const float* __restrict__ mean, const float* __restrict__ logvar,
    const float* __restrict__ eps,
    const ushort_t* __restrict__ wgl,
    float* __restrict__ out)
{
  const int tid  = threadIdx.x;
  const int wave = tid >> 6;
  const int lane = tid & 63;
  const int quad = lane >> 4;
  const int l15  = lane & 15;
  const int qc   = quad*4;
  const int rbase = blockIdx.x*64 + wave*32;

  const float* wsb = (const float*)(wgl + WGL_SHORTS);

  // row-per-lane D-state: z1D[t][nt*4+i] = row rbase+t*16+l15,
  // col (within half) nt*16+qc+i
  float z1D[2][16], z2D[2][16];
  float T[2];                        // 0.5*sum(lv+eps^2) + sum(log sig), partial

  // ---- init: z = eps*exp(0.5*lv)+mean, float4 loads ----
  #pragma unroll
  for (int t=0;t<2;++t){
    int rrow = rbase + t*16 + l15;
    int brow = rrow & (BB-1);
    const float* er = eps    + (size_t)rrow*ZSD;
    const float* mr = mean   + (size_t)brow*ZSD;
    const float* vr = logvar + (size_t)brow*ZSD;
    float acc = 0.f;
    #pragma unroll
    for (int nt=0;nt<4;++nt){
      int c1 = nt*16 + qc;
      int c2 = 64 + c1;
      f4 e1 = *(const f4*)(er + c1), v1 = *(const f4*)(vr + c1), m1 = *(const f4*)(mr + c1);
      f4 e2 = *(const f4*)(er + c2), v2 = *(const f4*)(vr + c2), m2 = *(const f4*)(mr + c2);
      #pragma unroll
      for (int i=0;i<4;++i){
        z1D[t][nt*4+i] = fmaf(e1[i], __expf(0.5f*v1[i]), m1[i]);
        z2D[t][nt*4+i] = fmaf(e2[i], __expf(0.5f*v2[i]), m2[i]);
        acc += (v1[i] + e1[i]*e1[i]) + (v2[i] + e2[i]*e2[i]);
      }
    }
    T[t] = 0.5f*acc;
  }

  // ---- 4 coupling steps (2 bodies in a non-unrolled loop to bound I$) ----
  #pragma unroll 1
  for (int it=0; it<2; ++it){
    do_step(2*it+0, z1D, z2D, T, wgl, wsb, quad, l15);
    do_step(2*it+1, z2D, z1D, T, wgl, wsb, quad, l15);
  }

  // ---- store z_out (fp32, float4) ----
  #pragma unroll
  for (int t=0;t<2;++t){
    int rrow = rbase + t*16 + l15;
    float* orow = out + (size_t)rrow*ZSD;
    #pragma unroll
    for (int nt=0;nt<4;++nt){
      f4 o1 = {z1D[t][nt*4+0], z1D[t][nt*4+1], z1D[t][nt*4+2], z1D[t][nt*4+3]};
      f4 o2 = {z2D[t][nt*4+0], z2D[t][nt*4+1], z2D[t][nt*4+2], z2D[t][nt*4+3]};
      *(f4*)(orow + nt*16 + qc)      = o1;
      *(f4*)(orow + 64 + nt*16 + qc) = o2;
    }
  }

  // ---- logpz: reduce T over the 4 quads (cols partitioned by quad) ----
  #pragma unroll
  for (int t=0;t<2;++t){
    float v = T[t];
    v += __shfl_xor(v, 16, 64);
    v += __shfl_xor(v, 32, 64);
    T[t] = v;
  }
  if (lane < 16){
    const float NC = -0.5f * 128.0f * 1.8378770664093453f;
    #pragma unroll
    for (int t=0;t<2;++t)
      out[(size_t)NROWS*ZSD + rbase + t*16 + l15] = NC - T[t];
  }
}

extern "C" void kernel_launch(void* const* d_in, const int* in_sizes, int n_in,
                              void* d_out, int out_size, void* d_ws, size_t ws_size,
                              hipStream_t stream)
{
  const float* mean   = (const float*)d_in[0];
  const float* logvar = (const float*)d_in[1];
  const float* eps    = (const float*)d_in[2];
  const float* W0     = (const float*)d_in[3];
  const float* b0     = (const float*)d_in[4];
  const float* W1     = (const float*)d_in[5];
  const float* b1     = (const float*)d_in[6];
  const float* W2     = (const float*)d_in[7];
  const float* b2     = (const float*)d_in[8];
  ushort_t* wgl = (ushort_t*)d_ws;          // ws_size >= 156448 proven round 3

  convert_weights<<<(WGL_SHORTS + 255)/256, 256, 0, stream>>>(W0,b0,W1,b1,W2,b2, wgl);
  flow_mfma<<<NROWS/64, 128, 0, stream>>>(mean, logvar, eps, wgl, (float*)d_out);
}

// Round 9
// 175.412 us; speedup vs baseline: 1.1691x; 1.0487x over previous
//
#include <hip/hip_runtime.h>

// Flow1: RealNVP coupling flow. K=32 B=4096 ZS=128 ZH=64 HS=50 NF=2.
// Round 13: revert to r9 structure (71 us; every departure lost: r10 80,
// r11 103, r12 82) + attack the TRANS PIPE. Evidence: VALU-busy TIME is
// invariant ~30 us across 6 structural variants; instruction count says only
// ~12 us is real 2-cy VALU -> ~18 us is the 560 transcendentals/lane at
// quarter rate, each tanh/sigmoid carrying TWO serial trans latencies.
// Change (single mechanism): Pade[5/6] rational activations, 1 rcp each,
// zero exp:  tanh x ~= x(10395+1260u+21u^2)/(10395+4725u+210u^2+u^3), u=x^2
// (continued-fraction depth 11). tanh: clamp x to +-5, err <=1.1e-3 (< bf16
// h-rounding; saturated region bit-identical after bf16). sigmoid =
// 0.5+0.5*tanh(x/2): |spre|<=7.21 hard bound (h<=1, |W2|<=0.1414, 50 terms)
// -> |y|<=3.61, NO clamp, err ~1e-4; logdet drift <=0.015.
// Trans/step: 64 exp + 64 rcp + 8 log -> 64 rcp + 8 log.
//
// Layouts (m89/m91-verified):
//   A-frag: A[m][k], m=lane&15, k=quad*8+j (j=0..7) per 32-K-tile
//   B-frag: B[k][n], n=lane&15, k=quad*8+j
//   C/D   : D[m][n], n=lane&15, m=quad*4+reg

typedef unsigned short ushort_t;
typedef unsigned int   uint_t;
typedef short bf8 __attribute__((ext_vector_type(8)));
typedef float f4  __attribute__((ext_vector_type(4)));

#define KK   32
#define BB   4096
#define ZSD  128
#define ZHD  64
#define HSD  50
#define NROWS (KK*BB)

#define WST  72                   // k-stride (shorts) for weight/act tiles
#define MATS (64*WST)             // shorts per padded matrix  = 4608
#define WGL_SHORTS (12*MATS)      // 55296 shorts = 110592 B
#define WS_BYTES   (WGL_SHORTS*2 + 768*4)   // + padded fp32 biases [4][3][64]

// hardware bf16 convert (RNE on gfx950)
__device__ __forceinline__ ushort_t f2bf(float f){
  union{__bf16 h; ushort_t u;} v; v.h = (__bf16)f; return v.u;
}

__device__ __forceinline__ float rcp_fast(float x){ return __builtin_amdgcn_rcpf(x); }

// Pade[5/6] tanh (continued fraction depth 11): err <=1.1e-3 on R with
// clamp to +-5; odd function, sign handled naturally. 1 trans (rcp), 0 exp.
__device__ __forceinline__ float tanh_pade(float x){
  float xc = fminf(fmaxf(x, -5.0f), 5.0f);
  float u  = xc*xc;
  float p  = fmaf(u, fmaf(u, 21.0f, 1260.0f), 10395.0f);
  float q  = fmaf(u, fmaf(u, u + 210.0f, 4725.0f), 10395.0f);
  return xc * p * rcp_fast(q);
}

// sigmoid(x) = 0.5 + 0.5*tanh(x/2); |x|<=7.21 by construction -> no clamp.
__device__ __forceinline__ float sigmoid_pade(float x){
  float y = 0.5f*x;
  float u = y*y;
  float p = fmaf(u, fmaf(u, 21.0f, 1260.0f), 10395.0f);
  float q = fmaf(u, fmaf(u, u + 210.0f, 4725.0f), 10395.0f);
  float t = y * p * rcp_fast(q);
  return fmaf(0.5f, t, 0.5f);
}

__device__ __forceinline__ f4 MFMA(bf8 a, bf8 b, f4 c){
  return __builtin_amdgcn_mfma_f32_16x16x32_bf16(a, b, c, 0, 0, 0);
}

// ---- weight preconversion: fp32 -> padded bf16 [step][mat][n][WST] + biases
__global__ void convert_weights(const float* __restrict__ W0g,
                                const float* __restrict__ b0g,
                                const float* __restrict__ W1g,
                                const float* __restrict__ b1g,
                                const float* __restrict__ W2g,
                                const float* __restrict__ b2g,
                                ushort_t* __restrict__ wgl)
{
  int t = blockIdx.x*256 + threadIdx.x;
  if (t < WGL_SHORTS){
    int mi  = t / MATS;             // step*3 + which
    int rem = t % MATS;
    int n   = rem / WST;
    int k   = rem % WST;
    int step  = mi / 3;
    int which = mi % 3;
    float v = 0.0f;
    if (which == 0){                           // B0[k=z][n=h] = W0[step][n][k]
      if (n < HSD && k < ZHD) v = W0g[(step*HSD + n)*ZHD + k];
    } else if (which == 1){                    // B1[k=h][n=z] = W1[step][n][k]
      if (k < HSD)            v = W1g[(step*ZHD + n)*HSD + k];
    } else {
      if (k < HSD)            v = W2g[(step*ZHD + n)*HSD + k];
    }
    wgl[t] = f2bf(v);
  }
  if (t < 768){                                // biases fp32 padded to 64
    float* bp = (float*)(wgl + WGL_SHORTS);
    int step  = t / 192;
    int rem   = t % 192;
    int which = rem / 64;
    int n     = rem % 64;
    float v = 0.0f;
    if (which == 0){ if (n < HSD) v = b0g[step*HSD + n]; }
    else if (which == 1) v = b1g[step*ZHD + n];
    else                 v = b2g[step*ZHD + n];
    bp[t] = v;
  }
}

// one coupling step; pz = passive-half registers (updated), active already in zAw
__device__ __forceinline__ void do_step(
    int s, float (&pz)[2][16], float (&T)[2][4],
    ushort_t* zAw, ushort_t* hAw,
    const ushort_t* wgl, const float* wsb,
    int quad, int l15, int wr)
{
  // this step's 3 matrices, read directly from global (L1/L2-resident)
  const ushort_t* ws = wgl + (size_t)(s*3)*MATS;

  // ---- phase A: H = tanh(Zact @ B0 + b0) ----
  bf8 zf[2][2];
  #pragma unroll
  for (int m=0;m<2;++m)
    #pragma unroll
    for (int kt=0;kt<2;++kt)
      zf[m][kt] = *(const bf8*)(zAw + (m*16 + l15)*WST + kt*32 + quad*8);

  #pragma unroll
  for (int nt=0;nt<4;++nt){
    const ushort_t* wb = ws + (0*64 + nt*16 + l15)*WST + quad*8;
    bf8 w0a = *(const bf8*)(wb);
    bf8 w0b = *(const bf8*)(wb + 32);
    float b0v = wsb[(s*3+0)*64 + nt*16 + l15];
    #pragma unroll
    for (int m=0;m<2;++m){
      f4 acc = {0.f,0.f,0.f,0.f};
      acc = MFMA(zf[m][0], w0a, acc);
      acc = MFMA(zf[m][1], w0b, acc);
      #pragma unroll
      for (int i=0;i<4;++i){
        float h = tanh_pade(acc[i] + b0v);
        hAw[(m*16 + quad*4 + i)*WST + nt*16 + l15] = f2bf(h);
      }
    }
  }

  // ---- phase B: MEW = H@B1 + b1 ; SIG = sigmoid(H@B2 + b2) ----
  bf8 hf[2][2];
  #pragma unroll
  for (int m=0;m<2;++m)
    #pragma unroll
    for (int kt=0;kt<2;++kt)
      hf[m][kt] = *(const bf8*)(hAw + (m*16 + l15)*WST + kt*32 + quad*8);

  // product-of-sigmoids accumulators: one log per (m,i) per step
  float sp[2][4];
  #pragma unroll
  for (int m=0;m<2;++m)
    #pragma unroll
    for (int i=0;i<4;++i) sp[m][i] = 1.0f;

  #pragma unroll
  for (int nt=0;nt<4;++nt){
    const ushort_t* w1p = ws + (1*64 + nt*16 + l15)*WST + quad*8;
    const ushort_t* w2p = ws + (2*64 + nt*16 + l15)*WST + quad*8;
    bf8 w1a = *(const bf8*)(w1p);
    bf8 w1b = *(const bf8*)(w1p + 32);
    bf8 w2a = *(const bf8*)(w2p);
    bf8 w2b = *(const bf8*)(w2p + 32);
    float b1v = wsb[(s*3+1)*64 + nt*16 + l15];
    float b2v = wsb[(s*3+2)*64 + nt*16 + l15];
    #pragma unroll
    for (int m=0;m<2;++m){
      f4 am = {0.f,0.f,0.f,0.f};
      f4 as = {0.f,0.f,0.f,0.f};
      am = MFMA(hf[m][0], w1a, am);
      am = MFMA(hf[m][1], w1b, am);
      as = MFMA(hf[m][0], w2a, as);
      as = MFMA(hf[m][1], w2b, as);
      #pragma unroll
      for (int i=0;i<4;++i){
        float mew  = am[i] + b1v;
        float spre = as[i] + b2v;
        float sig  = sigmoid_pade(spre);
        sp[m][i] *= sig;
        pz[m][nt*4+i] = fmaf(pz[m][nt*4+i], sig, mew);
      }
    }
  }

  // 4-term products >= (7.5e-4)^4 ~ 3e-13: safely above fp32 underflow
  #pragma unroll
  for (int m=0;m<2;++m)
    #pragma unroll
    for (int i=0;i<4;++i)
      T[m][i] += __logf(sp[m][i]);

  // new active = just-updated passive -> zA (bf16, A-layout)
  if (wr){
    #pragma unroll
    for (int m=0;m<2;++m)
      #pragma unroll
      for (int nt=0;nt<4;++nt)
        #pragma unroll
        for (int i=0;i<4;++i)
          zAw[(m*16 + quad*4 + i)*WST + nt*16 + l15] = f2bf(pz[m][nt*4+i]);
  }
}

__global__ __launch_bounds__(128) void flow_mfma(
    const float* __restrict__ mean, const float* __restrict__ logvar,
    const float* __restrict__ eps,
    const ushort_t* __restrict__ wgl,
    float* __restrict__ out)
{
  __shared__ __align__(16) ushort_t zA[2][32*WST];      // 2 x 4608 B
  __shared__ __align__(16) ushort_t hA[2][32*WST];      // 2 x 4608 B

  const int tid  = threadIdx.x;
  const int wave = tid >> 6;
  const int lane = tid & 63;
  const int quad = lane >> 4;
  const int l15  = lane & 15;
  const int rbase = blockIdx.x*64 + wave*32;

  const float* wsb = (const float*)(wgl + WGL_SHORTS);
  ushort_t* zAw = zA[wave];
  ushort_t* hAw = hA[wave];

  // z1D/z2D in C/D layout: [mtile][nt*4+reg] -> row=mtile*16+quad*4+reg,
  // col(z-index within half)=nt*16+l15
  float z1D[2][16], z2D[2][16];
  float T[2][4];                     // T = 0.5*sum(lv+eps^2) + sum(lsig)

  // ---- init: z = eps*exp(0.5*lv)+mean, loaded directly in D-layout ----
  #pragma unroll
  for (int m=0;m<2;++m){
    #pragma unroll
    for (int i=0;i<4;++i){
      int rrow = rbase + m*16 + quad*4 + i;
      int brow = rrow & (BB-1);
      const float* er = eps    + (size_t)rrow*ZSD;
      const float* mr = mean   + (size_t)brow*ZSD;
      const float* vr = logvar + (size_t)brow*ZSD;
      float acc = 0.f;
      #pragma unroll
      for (int nt=0;nt<4;++nt){
        int c1 = nt*16 + l15;
        int c2 = 64 + c1;
        float e1 = er[c1], v1 = vr[c1], m1 = mr[c1];
        float e2 = er[c2], v2 = vr[c2], m2 = mr[c2];
        z1D[m][nt*4+i] = fmaf(e1, __expf(0.5f*v1), m1);
        z2D[m][nt*4+i] = fmaf(e2, __expf(0.5f*v2), m2);
        acc += (v1 + e1*e1) + (v2 + e2*e2);
      }
      T[m][i] = 0.5f*acc;
    }
  }

  // initial active = z1 -> zA
  #pragma unroll
  for (int m=0;m<2;++m)
    #pragma unroll
    for (int nt=0;nt<4;++nt)
      #pragma unroll
      for (int i=0;i<4;++i)
        zAw[(m*16 + quad*4 + i)*WST + nt*16 + l15] = f2bf(z1D[m][nt*4+i]);

  // ---- 4 coupling steps (2 bodies in a non-unrolled loop to bound I$) ----
  #pragma unroll 1
  for (int it=0; it<2; ++it){
    do_step(2*it+0, z2D, T, zAw, hAw, wgl, wsb, quad, l15, 1);
    do_step(2*it+1, z1D, T, zAw, hAw, wgl, wsb, quad, l15, it==0);
  }

  // ---- store z_out (fp32) ----
  #pragma unroll
  for (int m=0;m<2;++m){
    #pragma unroll
    for (int i=0;i<4;++i){
      int rrow = rbase + m*16 + quad*4 + i;
      float* orow = out + (size_t)rrow*ZSD;
      #pragma unroll
      for (int nt=0;nt<4;++nt){
        orow[nt*16 + l15]      = z1D[m][nt*4+i];
        orow[64 + nt*16 + l15] = z2D[m][nt*4+i];
      }
    }
  }

  // ---- logpz = -0.5*128*ln(2pi) - T_rowsum ; reduce T across the 16 lanes
  // of each quad (they cover all 128 cols of rows quad*4+reg) ----
  #pragma unroll
  for (int m=0;m<2;++m)
    #pragma unroll
    for (int i=0;i<4;++i){
      float v = T[m][i];
      v += __shfl_xor(v, 1, 64);
      v += __shfl_xor(v, 2, 64);
      v += __shfl_xor(v, 4, 64);
      v += __shfl_xor(v, 8, 64);
      T[m][i] = v;
    }
  if (l15 == 0){
    const float NC = -0.5f * 128.0f * 1.8378770664093453f;
    #pragma unroll
    for (int m=0;m<2;++m)
      #pragma unroll
      for (int i=0;i<4;++i){
        int rrow = rbase + m*16 + quad*4 + i;
        out[(size_t)NROWS*ZSD + rrow] = NC - T[m][i];
      }
  }
}

extern "C" void kernel_launch(void* const* d_in, const int* in_sizes, int n_in,
                              void* d_out, int out_size, void* d_ws, size_t ws_size,
                              hipStream_t stream)
{
  const float* mean   = (const float*)d_in[0];
  const float* logvar = (const float*)d_in[1];
  const float* eps    = (const float*)d_in[2];
  const float* W0     = (const float*)d_in[3];
  const float* b0     = (const float*)d_in[4];
  const float* W1     = (const float*)d_in[5];
  const float* b1     = (const float*)d_in[6];
  const float* W2     = (const float*)d_in[7];
  const float* b2     = (const float*)d_in[8];
  ushort_t* wgl = (ushort_t*)d_ws;          // ws_size >= 156448 proven round 3

  convert_weights<<<(WGL_SHORTS + 255)/256, 256, 0, stream>>>(W0,b0,W1,b1,W2,b2, wgl);
  flow_mfma<<<NROWS/64, 128, 0, stream>>>(mean, logvar, eps, wgl, (float*)d_out);
}

// Round 10
// 174.394 us; speedup vs baseline: 1.1759x; 1.0058x over previous
//
#include <hip/hip_runtime.h>

// Flow1: RealNVP coupling flow. K=32 B=4096 ZS=128 ZH=64 HS=50 NF=2.
// Round 14: packed-FP32 activations (v_pk_fma_f32). Evidence: VALU-busy time
// invariant ~30-32us across SEVEN structural variants; r13's exp-removal null
// proves trans pipe irrelevant -> the 32us is plain VALU issue volume, of
// which activations are ~half (256 x ~17 ops). VOP3P v_pk_fma_f32 processes
// 2 f32/instr; MFMA's f4 acc is an aligned VGPR quad so acc[0:1]/acc[2:3]
// are free float2 pairs. Pade per pair: ~17 -> ~9 instrs (~1000 saved/lane).
// Everything else identical to r13 (= r9 structure, 71-73 us).
// Pade[5/6]: tanh x ~= x(10395+1260u+21u^2)/(10395+4725u+210u^2+u^3), u=x^2;
// tanh clamps +-5 (err<=1.1e-3 < bf16 step); sigmoid = 0.5+0.5*tanh(x/2),
// |spre|<=7.21 hard bound -> no clamp. Verified absmax 0.25 in r13.
//
// Layouts (m89/m91-verified):
//   A-frag: A[m][k], m=lane&15, k=quad*8+j (j=0..7) per 32-K-tile
//   B-frag: B[k][n], n=lane&15, k=quad*8+j
//   C/D   : D[m][n], n=lane&15, m=quad*4+reg

typedef unsigned short ushort_t;
typedef unsigned int   uint_t;
typedef short bf8 __attribute__((ext_vector_type(8)));
typedef float f4  __attribute__((ext_vector_type(4)));
typedef float f2  __attribute__((ext_vector_type(2)));

#define KK   32
#define BB   4096
#define ZSD  128
#define ZHD  64
#define HSD  50
#define NROWS (KK*BB)

#define WST  72                   // k-stride (shorts) for weight/act tiles
#define MATS (64*WST)             // shorts per padded matrix  = 4608
#define WGL_SHORTS (12*MATS)      // 55296 shorts = 110592 B
#define WS_BYTES   (WGL_SHORTS*2 + 768*4)   // + padded fp32 biases [4][3][64]

// hardware bf16 convert (RNE on gfx950)
__device__ __forceinline__ ushort_t f2bf(float f){
  union{__bf16 h; ushort_t u;} v; v.h = (__bf16)f; return v.u;
}

__device__ __forceinline__ float rcp_fast(float x){ return __builtin_amdgcn_rcpf(x); }

// packed 2xf32 fma (VOP3P, 64-bit VGPR pairs)
__device__ __forceinline__ f2 pk_fma(f2 a, f2 b, f2 c){
  f2 d;
  asm("v_pk_fma_f32 %0, %1, %2, %3" : "=v"(d) : "v"(a), "v"(b), "v"(c));
  return d;
}

struct PadeC {
  f2 c21, c1260, c10395, c210, c4725, chalf;
};

// Pade[5/6] tanh on a pair; clamp to +-5 done scalar per element.
__device__ __forceinline__ f2 tanh_pade2(f2 x, const PadeC& C){
  x.x = fminf(fmaxf(x.x, -5.0f), 5.0f);
  x.y = fminf(fmaxf(x.y, -5.0f), 5.0f);
  f2 u  = x*x;
  f2 p  = pk_fma(u, pk_fma(u, C.c21, C.c1260), C.c10395);
  f2 q  = pk_fma(u, pk_fma(u, u + C.c210, C.c4725), C.c10395);
  f2 xp = x*p;
  f2 r; r.x = xp.x*rcp_fast(q.x); r.y = xp.y*rcp_fast(q.y);
  return r;
}

// sigmoid(x) = 0.5 + 0.5*tanh(x/2); |x|<=7.21 by construction -> no clamp.
__device__ __forceinline__ f2 sigmoid_pade2(f2 x, const PadeC& C){
  f2 y  = 0.5f*x;
  f2 u  = y*y;
  f2 p  = pk_fma(u, pk_fma(u, C.c21, C.c1260), C.c10395);
  f2 q  = pk_fma(u, pk_fma(u, u + C.c210, C.c4725), C.c10395);
  f2 yp = y*p;
  f2 t; t.x = yp.x*rcp_fast(q.x); t.y = yp.y*rcp_fast(q.y);
  return pk_fma(t, C.chalf, C.chalf);
}

__device__ __forceinline__ f4 MFMA(bf8 a, bf8 b, f4 c){
  return __builtin_amdgcn_mfma_f32_16x16x32_bf16(a, b, c, 0, 0, 0);
}

// ---- weight preconversion: fp32 -> padded bf16 [step][mat][n][WST] + biases
__global__ void convert_weights(const float* __restrict__ W0g,
                                const float* __restrict__ b0g,
                                const float* __restrict__ W1g,
                                const float* __restrict__ b1g,
                                const float* __restrict__ W2g,
                                const float* __restrict__ b2g,
                                ushort_t* __restrict__ wgl)
{
  int t = blockIdx.x*256 + threadIdx.x;
  if (t < WGL_SHORTS){
    int mi  = t / MATS;             // step*3 + which
    int rem = t % MATS;
    int n   = rem / WST;
    int k   = rem % WST;
    int step  = mi / 3;
    int which = mi % 3;
    float v = 0.0f;
    if (which == 0){                           // B0[k=z][n=h] = W0[step][n][k]
      if (n < HSD && k < ZHD) v = W0g[(step*HSD + n)*ZHD + k];
    } else if (which == 1){                    // B1[k=h][n=z] = W1[step][n][k]
      if (k < HSD)            v = W1g[(step*ZHD + n)*HSD + k];
    } else {
      if (k < HSD)            v = W2g[(step*ZHD + n)*HSD + k];
    }
    wgl[t] = f2bf(v);
  }
  if (t < 768){                                // biases fp32 padded to 64
    float* bp = (float*)(wgl + WGL_SHORTS);
    int step  = t / 192;
    int rem   = t % 192;
    int which = rem / 64;
    int n     = rem % 64;
    float v = 0.0f;
    if (which == 0){ if (n < HSD) v = b0g[step*HSD + n]; }
    else if (which == 1) v = b1g[step*ZHD + n];
    else                 v = b2g[step*ZHD + n];
    bp[t] = v;
  }
}

// one coupling step; pz = passive-half registers (updated), active already in zAw
__device__ __forceinline__ void do_step(
    int s, float (&pz)[2][16], float (&T)[2][4],
    ushort_t* zAw, ushort_t* hAw,
    const ushort_t* wgl, const float* wsb,
    const PadeC& C,
    int quad, int l15, int wr)
{
  // this step's 3 matrices, read directly from global (L1/L2-resident)
  const ushort_t* ws = wgl + (size_t)(s*3)*MATS;

  // ---- phase A: H = tanh(Zact @ B0 + b0) ----
  bf8 zf[2][2];
  #pragma unroll
  for (int m=0;m<2;++m)
    #pragma unroll
    for (int kt=0;kt<2;++kt)
      zf[m][kt] = *(const bf8*)(zAw + (m*16 + l15)*WST + kt*32 + quad*8);

  #pragma unroll
  for (int nt=0;nt<4;++nt){
    const ushort_t* wb = ws + (0*64 + nt*16 + l15)*WST + quad*8;
    bf8 w0a = *(const bf8*)(wb);
    bf8 w0b = *(const bf8*)(wb + 32);
    float b0v = wsb[(s*3+0)*64 + nt*16 + l15];
    f2 b0p; b0p.x = b0v; b0p.y = b0v;
    #pragma unroll
    for (int m=0;m<2;++m){
      f4 acc = {0.f,0.f,0.f,0.f};
      acc = MFMA(zf[m][0], w0a, acc);
      acc = MFMA(zf[m][1], w0b, acc);
      f2 a01; a01.x = acc[0]; a01.y = acc[1];
      f2 a23; a23.x = acc[2]; a23.y = acc[3];
      f2 h01 = tanh_pade2(a01 + b0p, C);
      f2 h23 = tanh_pade2(a23 + b0p, C);
      hAw[(m*16 + quad*4 + 0)*WST + nt*16 + l15] = f2bf(h01.x);
      hAw[(m*16 + quad*4 + 1)*WST + nt*16 + l15] = f2bf(h01.y);
      hAw[(m*16 + quad*4 + 2)*WST + nt*16 + l15] = f2bf(h23.x);
      hAw[(m*16 + quad*4 + 3)*WST + nt*16 + l15] = f2bf(h23.y);
    }
  }

  // ---- phase B: MEW = H@B1 + b1 ; SIG = sigmoid(H@B2 + b2) ----
  bf8 hf[2][2];
  #pragma unroll
  for (int m=0;m<2;++m)
    #pragma unroll
    for (int kt=0;kt<2;++kt)
      hf[m][kt] = *(const bf8*)(hAw + (m*16 + l15)*WST + kt*32 + quad*8);

  // product-of-sigmoids accumulators: one log per (m,i) per step
  float sp[2][4];
  #pragma unroll
  for (int m=0;m<2;++m)
    #pragma unroll
    for (int i=0;i<4;++i) sp[m][i] = 1.0f;

  #pragma unroll
  for (int nt=0;nt<4;++nt){
    const ushort_t* w1p = ws + (1*64 + nt*16 + l15)*WST + quad*8;
    const ushort_t* w2p = ws + (2*64 + nt*16 + l15)*WST + quad*8;
    bf8 w1a = *(const bf8*)(w1p);
    bf8 w1b = *(const bf8*)(w1p + 32);
    bf8 w2a = *(const bf8*)(w2p);
    bf8 w2b = *(const bf8*)(w2p + 32);
    float b1v = wsb[(s*3+1)*64 + nt*16 + l15];
    float b2v = wsb[(s*3+2)*64 + nt*16 + l15];
    f2 b2p; b2p.x = b2v; b2p.y = b2v;
    #pragma unroll
    for (int m=0;m<2;++m){
      f4 am = {0.f,0.f,0.f,0.f};
      f4 as = {0.f,0.f,0.f,0.f};
      am = MFMA(hf[m][0], w1a, am);
      am = MFMA(hf[m][1], w1b, am);
      as = MFMA(hf[m][0], w2a, as);
      as = MFMA(hf[m][1], w2b, as);
      f2 s01 = sigmoid_pade2((f2){as[0], as[1]} + b2p, C);
      f2 s23 = sigmoid_pade2((f2){as[2], as[3]} + b2p, C);
      float sg[4] = {s01.x, s01.y, s23.x, s23.y};
      #pragma unroll
      for (int i=0;i<4;++i){
        float mew  = am[i] + b1v;
        sp[m][i] *= sg[i];
        pz[m][nt*4+i] = fmaf(pz[m][nt*4+i], sg[i], mew);
      }
    }
  }

  // 4-term products >= (7.5e-4)^4 ~ 3e-13: safely above fp32 underflow
  #pragma unroll
  for (int m=0;m<2;++m)
    #pragma unroll
    for (int i=0;i<4;++i)
      T[m][i] += __logf(sp[m][i]);

  // new active = just-updated passive -> zA (bf16, A-layout)
  if (wr){
    #pragma unroll
    for (int m=0;m<2;++m)
      #pragma unroll
      for (int nt=0;nt<4;++nt)
        #pragma unroll
        for (int i=0;i<4;++i)
          zAw[(m*16 + quad*4 + i)*WST + nt*16 + l15] = f2bf(pz[m][nt*4+i]);
  }
}

__global__ __launch_bounds__(128) void flow_mfma(
    const float* __restrict__ mean, const float* __restrict__ logvar,
    const float* __restrict__ eps,
    const ushort_t* __restrict__ wgl,
    float* __restrict__ out)
{
  __shared__ __align__(16) ushort_t zA[2][32*WST];      // 2 x 4608 B
  __shared__ __align__(16) ushort_t hA[2][32*WST];      // 2 x 4608 B

  const int tid  = threadIdx.x;
  const int wave = tid >> 6;
  const int lane = tid & 63;
  const int quad = lane >> 4;
  const int l15  = lane & 15;
  const int rbase = blockIdx.x*64 + wave*32;

  const float* wsb = (const float*)(wgl + WGL_SHORTS);
  ushort_t* zAw = zA[wave];
  ushort_t* hAw = hA[wave];

  PadeC C;
  C.c21    = (f2){21.0f, 21.0f};
  C.c1260  = (f2){1260.0f, 1260.0f};
  C.c10395 = (f2){10395.0f, 10395.0f};
  C.c210   = (f2){210.0f, 210.0f};
  C.c4725  = (f2){4725.0f, 4725.0f};
  C.chalf  = (f2){0.5f, 0.5f};

  // z1D/z2D in C/D layout: [mtile][nt*4+reg] -> row=mtile*16+quad*4+reg,
  // col(z-index within half)=nt*16+l15
  float z1D[2][16], z2D[2][16];
  float T[2][4];                     // T = 0.5*sum(lv+eps^2) + sum(lsig)

  // ---- init: z = eps*exp(0.5*lv)+mean, loaded directly in D-layout ----
  #pragma unroll
  for (int m=0;m<2;++m){
    #pragma unroll
    for (int i=0;i<4;++i){
      int rrow = rbase + m*16 + quad*4 + i;
      int brow = rrow & (BB-1);
      const float* er = eps    + (size_t)rrow*ZSD;
      const float* mr = mean   + (size_t)brow*ZSD;
      const float* vr = logvar + (size_t)brow*ZSD;
      float acc = 0.f;
      #pragma unroll
      for (int nt=0;nt<4;++nt){
        int c1 = nt*16 + l15;
        int c2 = 64 + c1;
        float e1 = er[c1], v1 = vr[c1], m1 = mr[c1];
        float e2 = er[c2], v2 = vr[c2], m2 = mr[c2];
        z1D[m][nt*4+i] = fmaf(e1, __expf(0.5f*v1), m1);
        z2D[m][nt*4+i] = fmaf(e2, __expf(0.5f*v2), m2);
        acc += (v1 + e1*e1) + (v2 + e2*e2);
      }
      T[m][i] = 0.5f*acc;
    }
  }

  // initial active = z1 -> zA
  #pragma unroll
  for (int m=0;m<2;++m)
    #pragma unroll
    for (int nt=0;nt<4;++nt)
      #pragma unroll
      for (int i=0;i<4;++i)
        zAw[(m*16 + quad*4 + i)*WST + nt*16 + l15] = f2bf(z1D[m][nt*4+i]);

  // ---- 4 coupling steps (2 bodies in a non-unrolled loop to bound I$) ----
  #pragma unroll 1
  for (int it=0; it<2; ++it){
    do_step(2*it+0, z2D, T, zAw, hAw, wgl, wsb, C, quad, l15, 1);
    do_step(2*it+1, z1D, T, zAw, hAw, wgl, wsb, C, quad, l15, it==0);
  }

  // ---- store z_out (fp32) ----
  #pragma unroll
  for (int m=0;m<2;++m){
    #pragma unroll
    for (int i=0;i<4;++i){
      int rrow = rbase + m*16 + quad*4 + i;
      float* orow = out + (size_t)rrow*ZSD;
      #pragma unroll
      for (int nt=0;nt<4;++nt){
        orow[nt*16 + l15]      = z1D[m][nt*4+i];
        orow[64 + nt*16 + l15] = z2D[m][nt*4+i];
      }
    }
  }

  // ---- logpz = -0.5*128*ln(2pi) - T_rowsum ; reduce T across the 16 lanes
  // of each quad (they cover all 128 cols of rows quad*4+reg) ----
  #pragma unroll
  for (int m=0;m<2;++m)
    #pragma unroll
    for (int i=0;i<4;++i){
      float v = T[m][i];
      v += __shfl_xor(v, 1, 64);
      v += __shfl_xor(v, 2, 64);
      v += __shfl_xor(v, 4, 64);
      v += __shfl_xor(v, 8, 64);
      T[m][i] = v;
    }
  if (l15 == 0){
    const float NC = -0.5f * 128.0f * 1.8378770664093453f;
    #pragma unroll
    for (int m=0;m<2;++m)
      #pragma unroll
      for (int i=0;i<4;++i){
        int rrow = rbase + m*16 + quad*4 + i;
        out[(size_t)NROWS*ZSD + rrow] = NC - T[m][i];
      }
  }
}

extern "C" void kernel_launch(void* const* d_in, const int* in_sizes, int n_in,
                              void* d_out, int out_size, void* d_ws, size_t ws_size,
                              hipStream_t stream)
{
  const float* mean   = (const float*)d_in[0];
  const float* logvar = (const float*)d_in[1];
  const float* eps    = (const float*)d_in[2];
  const float* W0     = (const float*)d_in[3];
  const float* b0     = (const float*)d_in[4];
  const float* W1     = (const float*)d_in[5];
  const float* b1     = (const float*)d_in[6];
  const float* W2     = (const float*)d_in[7];
  const float* b2     = (const float*)d_in[8];
  ushort_t* wgl = (ushort_t*)d_ws;          // ws_size >= 156448 proven round 3

  convert_weights<<<(WGL_SHORTS + 255)/256, 256, 0, stream>>>(W0,b0,W1,b1,W2,b2, wgl);
  flow_mfma<<<NROWS/64, 128, 0, stream>>>(mean, logvar, eps, wgl, (float*)d_out);
}

// Round 11
// 172.251 us; speedup vs baseline: 1.1906x; 1.0124x over previous
//
#include <hip/hip_runtime.h>

// Flow1: RealNVP coupling flow. K=32 B=4096 ZS=128 ZH=64 HS=50 NF=2.
// Round 15: COALESCED weight fragments. Evidence: duration pinned 71-73 us
// across 5 falsified theories (occupancy r8, ILP r11, LDS r12, trans r13,
// issue volume r14 - busy time fell 32->28 us with NO duration change).
// Remaining untouched stream: weight loads. r14 reads 16B/lane at 144B row
// stride -> one wave load touches 64 cache lines (vs 16 coalesced); 24 such
// loads/step/wave x 16 waves/CU hammer one L1. Fix: fragment-major weight
// layout [mat][nt][kt][lane][8 shorts] -> every weight load is a contiguous
// 1024B wave read. Values identical (stored[n=nt*16+l15][k=kt*32+quad*8+j]);
// only addresses permute. do_step/MFMA/activations byte-identical to r14.
//
// Layouts (m89/m91-verified):
//   A-frag: A[m][k], m=lane&15, k=quad*8+j (j=0..7) per 32-K-tile
//   B-frag: B[k][n], n=lane&15, k=quad*8+j
//   C/D   : D[m][n], n=lane&15, m=quad*4+reg

typedef unsigned short ushort_t;
typedef unsigned int   uint_t;
typedef short bf8 __attribute__((ext_vector_type(8)));
typedef float f4  __attribute__((ext_vector_type(4)));
typedef float f2  __attribute__((ext_vector_type(2)));

#define KK   32
#define BB   4096
#define ZSD  128
#define ZHD  64
#define HSD  50
#define NROWS (KK*BB)

// fragment-major weights: per matrix 4nt x 2kt x 64lane x 8shorts = 4096
#define MATS2 4096
#define WGL_SHORTS (12*MATS2)     // 49152 shorts = 98304 B
#define WS_BYTES   (WGL_SHORTS*2 + 768*4)

// hardware bf16 convert (RNE on gfx950)
__device__ __forceinline__ ushort_t f2bf(float f){
  union{__bf16 h; ushort_t u;} v; v.h = (__bf16)f; return v.u;
}

__device__ __forceinline__ float rcp_fast(float x){ return __builtin_amdgcn_rcpf(x); }

// packed 2xf32 fma (VOP3P, 64-bit VGPR pairs)
__device__ __forceinline__ f2 pk_fma(f2 a, f2 b, f2 c){
  f2 d;
  asm("v_pk_fma_f32 %0, %1, %2, %3" : "=v"(d) : "v"(a), "v"(b), "v"(c));
  return d;
}

struct PadeC {
  f2 c21, c1260, c10395, c210, c4725, chalf;
};

// Pade[5/6] tanh on a pair; clamp to +-5 done scalar per element.
__device__ __forceinline__ f2 tanh_pade2(f2 x, const PadeC& C){
  x.x = fminf(fmaxf(x.x, -5.0f), 5.0f);
  x.y = fminf(fmaxf(x.y, -5.0f), 5.0f);
  f2 u  = x*x;
  f2 p  = pk_fma(u, pk_fma(u, C.c21, C.c1260), C.c10395);
  f2 q  = pk_fma(u, pk_fma(u, u + C.c210, C.c4725), C.c10395);
  f2 xp = x*p;
  f2 r; r.x = xp.x*rcp_fast(q.x); r.y = xp.y*rcp_fast(q.y);
  return r;
}

// sigmoid(x) = 0.5 + 0.5*tanh(x/2); |x|<=7.21 by construction -> no clamp.
__device__ __forceinline__ f2 sigmoid_pade2(f2 x, const PadeC& C){
  f2 y  = 0.5f*x;
  f2 u  = y*y;
  f2 p  = pk_fma(u, pk_fma(u, C.c21, C.c1260), C.c10395);
  f2 q  = pk_fma(u, pk_fma(u, u + C.c210, C.c4725), C.c10395);
  f2 yp = y*p;
  f2 t; t.x = yp.x*rcp_fast(q.x); t.y = yp.y*rcp_fast(q.y);
  return pk_fma(t, C.chalf, C.chalf);
}

__device__ __forceinline__ f4 MFMA(bf8 a, bf8 b, f4 c){
  return __builtin_amdgcn_mfma_f32_16x16x32_bf16(a, b, c, 0, 0, 0);
}

// ---- weight preconversion: fp32 -> fragment-major bf16 + fp32 biases.
// t -> (mat, nt, kt, lane, j); value = stored[n=nt*16+(lane&15)]
//                                        [k=kt*32+(lane>>4)*8+j]
// stored0 = W0[h=n][z=k]; stored1/2 = W1/W2[z=n][h=k].
__global__ void convert_weights(const float* __restrict__ W0g,
                                const float* __restrict__ b0g,
                                const float* __restrict__ W1g,
                                const float* __restrict__ b1g,
                                const float* __restrict__ W2g,
                                const float* __restrict__ b2g,
                                ushort_t* __restrict__ wgl)
{
  int t = blockIdx.x*256 + threadIdx.x;
  if (t < WGL_SHORTS){
    int mi   = t / MATS2;            // step*3 + which
    int rem  = t % MATS2;
    int nt   = rem / 1024;
    int rem2 = rem % 1024;
    int kt   = rem2 / 512;
    int rem3 = rem2 % 512;
    int lane = rem3 / 8;
    int j    = rem3 % 8;
    int l15  = lane & 15;
    int quad = lane >> 4;
    int n    = nt*16 + l15;
    int k    = kt*32 + quad*8 + j;
    int step  = mi / 3;
    int which = mi % 3;
    float v = 0.0f;
    if (which == 0){                           // W0[h=n][z=k], k<64 always
      if (n < HSD)  v = W0g[(step*HSD + n)*ZHD + k];
    } else if (which == 1){                    // W1[z=n][h=k]
      if (k < HSD)  v = W1g[(step*ZHD + n)*HSD + k];
    } else {                                   // W2[z=n][h=k]
      if (k < HSD)  v = W2g[(step*ZHD + n)*HSD + k];
    }
    wgl[t] = f2bf(v);
  }
  if (t < 768){                                // biases fp32 padded to 64
    float* bp = (float*)(wgl + WGL_SHORTS);
    int step  = t / 192;
    int rem   = t % 192;
    int which = rem / 64;
    int n     = rem % 64;
    float v = 0.0f;
    if (which == 0){ if (n < HSD) v = b0g[step*HSD + n]; }
    else if (which == 1) v = b1g[step*ZHD + n];
    else                 v = b2g[step*ZHD + n];
    bp[t] = v;
  }
}

// one coupling step; pz = passive-half registers (updated), active already in zAw
__device__ __forceinline__ void do_step(
    int s, float (&pz)[2][16], float (&T)[2][4],
    ushort_t* zAw, ushort_t* hAw,
    const ushort_t* wgl, const float* wsb,
    const PadeC& C,
    int quad, int l15, int lofs, int wr)
{
  // this step's 3 matrices, fragment-major (all loads coalesced 1024B/wave)
  const ushort_t* ws = wgl + (size_t)s*3*MATS2;

  #define WST 72   // LDS activation tile k-stride (shorts), unchanged

  // ---- phase A: H = tanh(Zact @ B0 + b0) ----
  bf8 zf[2][2];
  #pragma unroll
  for (int m=0;m<2;++m)
    #pragma unroll
    for (int kt=0;kt<2;++kt)
      zf[m][kt] = *(const bf8*)(zAw + (m*16 + l15)*WST + kt*32 + quad*8);

  #pragma unroll
  for (int nt=0;nt<4;++nt){
    const ushort_t* wb = ws + nt*1024 + lofs;          // mat0, kt=0 / kt=1
    bf8 w0a = *(const bf8*)(wb);
    bf8 w0b = *(const bf8*)(wb + 512);
    float b0v = wsb[(s*3+0)*64 + nt*16 + l15];
    f2 b0p; b0p.x = b0v; b0p.y = b0v;
    #pragma unroll
    for (int m=0;m<2;++m){
      f4 acc = {0.f,0.f,0.f,0.f};
      acc = MFMA(zf[m][0], w0a, acc);
      acc = MFMA(zf[m][1], w0b, acc);
      f2 a01; a01.x = acc[0]; a01.y = acc[1];
      f2 a23; a23.x = acc[2]; a23.y = acc[3];
      f2 h01 = tanh_pade2(a01 + b0p, C);
      f2 h23 = tanh_pade2(a23 + b0p, C);
      hAw[(m*16 + quad*4 + 0)*WST + nt*16 + l15] = f2bf(h01.x);
      hAw[(m*16 + quad*4 + 1)*WST + nt*16 + l15] = f2bf(h01.y);
      hAw[(m*16 + quad*4 + 2)*WST + nt*16 + l15] = f2bf(h23.x);
      hAw[(m*16 + quad*4 + 3)*WST + nt*16 + l15] = f2bf(h23.y);
    }
  }

  // ---- phase B: MEW = H@B1 + b1 ; SIG = sigmoid(H@B2 + b2) ----
  bf8 hf[2][2];
  #pragma unroll
  for (int m=0;m<2;++m)
    #pragma unroll
    for (int kt=0;kt<2;++kt)
      hf[m][kt] = *(const bf8*)(hAw + (m*16 + l15)*WST + kt*32 + quad*8);

  // product-of-sigmoids accumulators: one log per (m,i) per step
  float sp[2][4];
  #pragma unroll
  for (int m=0;m<2;++m)
    #pragma unroll
    for (int i=0;i<4;++i) sp[m][i] = 1.0f;

  #pragma unroll
  for (int nt=0;nt<4;++nt){
    const ushort_t* w1p = ws + 4096 + nt*1024 + lofs;  // mat1
    const ushort_t* w2p = ws + 8192 + nt*1024 + lofs;  // mat2
    bf8 w1a = *(const bf8*)(w1p);
    bf8 w1b = *(const bf8*)(w1p + 512);
    bf8 w2a = *(const bf8*)(w2p);
    bf8 w2b = *(const bf8*)(w2p + 512);
    float b1v = wsb[(s*3+1)*64 + nt*16 + l15];
    float b2v = wsb[(s*3+2)*64 + nt*16 + l15];
    f2 b2p; b2p.x = b2v; b2p.y = b2v;
    #pragma unroll
    for (int m=0;m<2;++m){
      f4 am = {0.f,0.f,0.f,0.f};
      f4 as = {0.f,0.f,0.f,0.f};
      am = MFMA(hf[m][0], w1a, am);
      am = MFMA(hf[m][1], w1b, am);
      as = MFMA(hf[m][0], w2a, as);
      as = MFMA(hf[m][1], w2b, as);
      f2 s01 = sigmoid_pade2((f2){as[0], as[1]} + b2p, C);
      f2 s23 = sigmoid_pade2((f2){as[2], as[3]} + b2p, C);
      float sg[4] = {s01.x, s01.y, s23.x, s23.y};
      #pragma unroll
      for (int i=0;i<4;++i){
        float mew  = am[i] + b1v;
        sp[m][i] *= sg[i];
        pz[m][nt*4+i] = fmaf(pz[m][nt*4+i], sg[i], mew);
      }
    }
  }

  // 4-term products >= (7.5e-4)^4 ~ 3e-13: safely above fp32 underflow
  #pragma unroll
  for (int m=0;m<2;++m)
    #pragma unroll
    for (int i=0;i<4;++i)
      T[m][i] += __logf(sp[m][i]);

  // new active = just-updated passive -> zA (bf16, A-layout)
  if (wr){
    #pragma unroll
    for (int m=0;m<2;++m)
      #pragma unroll
      for (int nt=0;nt<4;++nt)
        #pragma unroll
        for (int i=0;i<4;++i)
          zAw[(m*16 + quad*4 + i)*WST + nt*16 + l15] = f2bf(pz[m][nt*4+i]);
  }
}

__global__ __launch_bounds__(128) void flow_mfma(
    const float* __restrict__ mean, const float* __restrict__ logvar,
    const float* __restrict__ eps,
    const ushort_t* __restrict__ wgl,
    float* __restrict__ out)
{
  __shared__ __align__(16) ushort_t zA[2][32*WST];      // 2 x 4608 B
  __shared__ __align__(16) ushort_t hA[2][32*WST];      // 2 x 4608 B

  const int tid  = threadIdx.x;
  const int wave = tid >> 6;
  const int lane = tid & 63;
  const int quad = lane >> 4;
  const int l15  = lane & 15;
  const int lofs = lane*8;
  const int rbase = blockIdx.x*64 + wave*32;

  const float* wsb = (const float*)(wgl + WGL_SHORTS);
  ushort_t* zAw = zA[wave];
  ushort_t* hAw = hA[wave];

  PadeC C;
  C.c21    = (f2){21.0f, 21.0f};
  C.c1260  = (f2){1260.0f, 1260.0f};
  C.c10395 = (f2){10395.0f, 10395.0f};
  C.c210   = (f2){210.0f, 210.0f};
  C.c4725  = (f2){4725.0f, 4725.0f};
  C.chalf  = (f2){0.5f, 0.5f};

  // z1D/z2D in C/D layout: [mtile][nt*4+reg] -> row=mtile*16+quad*4+reg,
  // col(z-index within half)=nt*16+l15
  float z1D[2][16], z2D[2][16];
  float T[2][4];                     // T = 0.5*sum(lv+eps^2) + sum(lsig)

  // ---- init: z = eps*exp(0.5*lv)+mean, loaded directly in D-layout ----
  #pragma unroll
  for (int m=0;m<2;++m){
    #pragma unroll
    for (int i=0;i<4;++i){
      int rrow = rbase + m*16 + quad*4 + i;
      int brow = rrow & (BB-1);
      const float* er = eps    + (size_t)rrow*ZSD;
      const float* mr = mean   + (size_t)brow*ZSD;
      const float* vr = logvar + (size_t)brow*ZSD;
      float acc = 0.f;
      #pragma unroll
      for (int nt=0;nt<4;++nt){
        int c1 = nt*16 + l15;
        int c2 = 64 + c1;
        float e1 = er[c1], v1 = vr[c1], m1 = mr[c1];
        float e2 = er[c2], v2 = vr[c2], m2 = mr[c2];
        z1D[m][nt*4+i] = fmaf(e1, __expf(0.5f*v1), m1);
        z2D[m][nt*4+i] = fmaf(e2, __expf(0.5f*v2), m2);
        acc += (v1 + e1*e1) + (v2 + e2*e2);
      }
      T[m][i] = 0.5f*acc;
    }
  }

  // initial active = z1 -> zA
  #pragma unroll
  for (int m=0;m<2;++m)
    #pragma unroll
    for (int nt=0;nt<4;++nt)
      #pragma unroll
      for (int i=0;i<4;++i)
        zAw[(m*16 + quad*4 + i)*WST + nt*16 + l15] = f2bf(z1D[m][nt*4+i]);

  // ---- 4 coupling steps (2 bodies in a non-unrolled loop to bound I$) ----
  #pragma unroll 1
  for (int it=0; it<2; ++it){
    do_step(2*it+0, z2D, T, zAw, hAw, wgl, wsb, C, quad, l15, lofs, 1);
    do_step(2*it+1, z1D, T, zAw, hAw, wgl, wsb, C, quad, l15, lofs, it==0);
  }

  // ---- store z_out (fp32) ----
  #pragma unroll
  for (int m=0;m<2;++m){
    #pragma unroll
    for (int i=0;i<4;++i){
      int rrow = rbase + m*16 + quad*4 + i;
      float* orow = out + (size_t)rrow*ZSD;
      #pragma unroll
      for (int nt=0;nt<4;++nt){
        orow[nt*16 + l15]      = z1D[m][nt*4+i];
        orow[64 + nt*16 + l15] = z2D[m][nt*4+i];
      }
    }
  }

  // ---- logpz = -0.5*128*ln(2pi) - T_rowsum ; reduce T across the 16 lanes
  // of each quad (they cover all 128 cols of rows quad*4+reg) ----
  #pragma unroll
  for (int m=0;m<2;++m)
    #pragma unroll
    for (int i=0;i<4;++i){
      float v = T[m][i];
      v += __shfl_xor(v, 1, 64);
      v += __shfl_xor(v, 2, 64);
      v += __shfl_xor(v, 4, 64);
      v += __shfl_xor(v, 8, 64);
      T[m][i] = v;
    }
  if (l15 == 0){
    const float NC = -0.5f * 128.0f * 1.8378770664093453f;
    #pragma unroll
    for (int m=0;m<2;++m)
      #pragma unroll
      for (int i=0;i<4;++i){
        int rrow = rbase + m*16 + quad*4 + i;
        out[(size_t)NROWS*ZSD + rrow] = NC - T[m][i];
      }
  }
}

extern "C" void kernel_launch(void* const* d_in, const int* in_sizes, int n_in,
                              void* d_out, int out_size, void* d_ws, size_t ws_size,
                              hipStream_t stream)
{
  const float* mean   = (const float*)d_in[0];
  const float* logvar = (const float*)d_in[1];
  const float* eps    = (const float*)d_in[2];
  const float* W0     = (const float*)d_in[3];
  const float* b0     = (const float*)d_in[4];
  const float* W1     = (const float*)d_in[5];
  const float* b1     = (const float*)d_in[6];
  const float* W2     = (const float*)d_in[7];
  const float* b2     = (const float*)d_in[8];
  ushort_t* wgl = (ushort_t*)d_ws;          // ws_size >= 156448 proven round 3

  convert_weights<<<(WGL_SHORTS + 255)/256, 256, 0, stream>>>(W0,b0,W1,b1,W2,b2, wgl);
  flow_mfma<<<NROWS/64, 128, 0, stream>>>(mean, logvar, eps, wgl, (float*)d_out);
}